// Round 7
// baseline (52.169 us; speedup 1.0000x reference)
//
#include <hip/hip_runtime.h>

// KalmanGain: B=262144, N=8, M=4, fp32.
// Round 7: R6 math unchanged; SINGLE-WAVE blocks for phase desynchronization.
//   Block = 64 threads (1 wave), 16 batches, 4 lanes/batch (2 rows each).
//   LDS = 10 KB/block -> 16 blocks/CU = 16 waves/CU, each block an
//   independently-phased pipeline (vs 4 lock-stepped 4-wave gangs in R6).
//   With blockDim=64, __syncthreads() needs no s_barrier (wave-internal),
//   so sync points stall only this block; 15 others keep HBM fed.
// LDS (float4 granules): F/Q [0,256) | Sp [256,512) | H [512,640).
// R: lane p loads granule 4b+p directly (coalesced).
// Swizzle (rule 21 both-sides): LDS slot (b,j) holds global granule
// k = j ^ (b & mask); reads XOR the same mask. gl_lds dest stays linear.
// Schedule (R4/R6-proven):
//   issue F,H,Sp staging + R reg load ; sync(drain) ;
//   read fr,hs ; u = (HF)^T partial ; butterfly x2 ; sync (F dead) ;
//   issue Q into F slots ; G = fr@Sp ; A = G@u ; sync(drain Q) ;
//   A += Qown@H^T ; S = H A + R ; butterfly x2 ; inv(S) ; KG ; store.

#define NBB 16
#define THREADS 64

__device__ __forceinline__ void gl_lds16(const float* src, float4* dst) {
    __builtin_amdgcn_global_load_lds(
        (const __attribute__((address_space(1))) unsigned int*)src,
        (__attribute__((address_space(3))) unsigned int*)dst,
        16, 0, 0);
}

__global__ __launch_bounds__(THREADS) void kalman_gain_kernel(
    const float* __restrict__ Fg, const float* __restrict__ Hg,
    const float* __restrict__ Spg, const float* __restrict__ Qg,
    const float* __restrict__ Rg, float* __restrict__ out, int nb)
{
    __shared__ float4 smem4[640];    // 10240 B -> 16 blocks/CU

    const int lane = threadIdx.x;    // 0..63 (one wave)
    const int b0   = blockIdx.x * NBB;

    // ---- issue staging: F (4), H (2), Sp (4) wave-instructions ----
    #pragma unroll
    for (int r = 0; r < 4; ++r) {                // F: 256 granules
        int s = (r << 6) | lane;
        int b = s >> 4, j = s & 15, k = j ^ (b & 15);
        gl_lds16(Fg + (size_t)(b0 + b) * 64 + k * 4, smem4 + (r << 6));
    }
    #pragma unroll
    for (int r = 0; r < 2; ++r) {                // H: 128 granules
        int s = (r << 6) | lane;
        int b = s >> 3, j = s & 7, k = j ^ (b & 7);
        gl_lds16(Hg + (size_t)(b0 + b) * 32 + k * 4, smem4 + 512 + (r << 6));
    }
    #pragma unroll
    for (int r = 0; r < 4; ++r) {                // Sp: 256 granules
        int s = (r << 6) | lane;
        int b = s >> 4, j = s & 15, k = j ^ (b & 15);
        gl_lds16(Spg + (size_t)(b0 + b) * 64 + k * 4, smem4 + 256 + (r << 6));
    }

    const int b_loc = lane >> 2;     // 0..15
    const int p     = lane & 3;      // owns global rows 2p, 2p+1
    const int bm15  = b_loc & 15;
    const int bm7   = b_loc & 7;

    // ---- R own row: lane p loads granule 4*b + p (fully coalesced) ----
    const float4 Rr = *(reinterpret_cast<const float4*>(Rg)
                        + (size_t)(b0 + b_loc) * 4 + p);

    __syncthreads();   // 1-wave block: drains staging, no s_barrier cost

    // ---- hs[j][rl] = H[j][2p+rl], rl=0..1 (value select on p&1) ----
    float hs[8];
    #pragma unroll
    for (int j = 0; j < 4; ++j) {
        float4 v = smem4[512 + b_loc * 8 + ((2 * j + (p >> 1)) ^ bm7)];
        hs[j*2+0] = (p & 1) ? v.z : v.x;
        hs[j*2+1] = (p & 1) ? v.w : v.y;
    }

    // ---- fr = own 2 F rows [2][8] (granules 4p..4p+3) ----
    float fr[16];
    #pragma unroll
    for (int i = 0; i < 4; ++i) {
        float4 v = smem4[b_loc * 16 + ((4 * p + i) ^ bm15)];
        fr[i*4+0] = v.x; fr[i*4+1] = v.y; fr[i*4+2] = v.z; fr[i*4+3] = v.w;
    }

    // ---- u = (H F)^T [8][4]: own-row partial, 2-stage butterfly ----
    float u[32];
    #pragma unroll
    for (int x = 0; x < 32; ++x) u[x] = 0.f;
    #pragma unroll
    for (int rl = 0; rl < 2; ++rl)
        #pragma unroll
        for (int k = 0; k < 8; ++k)
            #pragma unroll
            for (int j = 0; j < 4; ++j)
                u[k*4+j] += hs[j*2+rl] * fr[rl*8+k];
    #pragma unroll
    for (int x = 0; x < 32; ++x) u[x] += __shfl_xor(u[x], 1, 64);
    #pragma unroll
    for (int x = 0; x < 32; ++x) u[x] += __shfl_xor(u[x], 2, 64);

    __syncthreads();   // all lanes done reading F LDS -> F buffer reusable

    // ---- issue Q (4) into F's LDS slots (hidden under G/A compute) ----
    #pragma unroll
    for (int r = 0; r < 4; ++r) {
        int s = (r << 6) | lane;
        int b = s >> 4, j = s & 15, k = j ^ (b & 15);
        gl_lds16(Qg + (size_t)(b0 + b) * 64 + k * 4, smem4 + (r << 6));
    }

    // ---- G = own F rows @ Sp  [2][8] (stream Sp rows from LDS) ----
    float G[16];
    #pragma unroll
    for (int x = 0; x < 16; ++x) G[x] = 0.f;
    #pragma unroll
    for (int k = 0; k < 8; ++k) {
        float4 s0 = smem4[256 + b_loc * 16 + ((2*k    ) ^ bm15)];
        float4 s1 = smem4[256 + b_loc * 16 + ((2*k + 1) ^ bm15)];
        float sp[8] = {s0.x,s0.y,s0.z,s0.w, s1.x,s1.y,s1.z,s1.w};
        #pragma unroll
        for (int il = 0; il < 2; ++il)
            #pragma unroll
            for (int c = 0; c < 8; ++c)
                G[il*8+c] += fr[il*8+k] * sp[c];
    }

    // ---- A = G @ u  [2][4] ----
    float A[8];
    #pragma unroll
    for (int il = 0; il < 2; ++il)
        #pragma unroll
        for (int j = 0; j < 4; ++j) {
            float acc = 0.f;
            #pragma unroll
            for (int k = 0; k < 8; ++k)
                acc += G[il*8+k] * u[k*4+j];
            A[il*4+j] = acc;
        }

    __syncthreads();   // drains Q staging (wave-internal)

    // ---- A += Qown @ H^T ----
    float qo[16];
    #pragma unroll
    for (int i = 0; i < 4; ++i) {
        float4 v = smem4[b_loc * 16 + ((4 * p + i) ^ bm15)];
        qo[i*4+0] = v.x; qo[i*4+1] = v.y; qo[i*4+2] = v.z; qo[i*4+3] = v.w;
    }
    #pragma unroll
    for (int j = 0; j < 4; ++j) {
        float4 h0 = smem4[512 + b_loc * 8 + ((2*j    ) ^ bm7)];
        float4 h1 = smem4[512 + b_loc * 8 + ((2*j + 1) ^ bm7)];
        float hrow[8] = {h0.x,h0.y,h0.z,h0.w, h1.x,h1.y,h1.z,h1.w};
        #pragma unroll
        for (int il = 0; il < 2; ++il) {
            float acc = 0.f;
            #pragma unroll
            for (int k = 0; k < 8; ++k)
                acc += qo[il*8+k] * hrow[k];
            A[il*4+j] += acc;
        }
    }

    // ---- S = H A + R: own partial (+own R row), 2-stage butterfly ----
    float s[16];
    #pragma unroll
    for (int pi = 0; pi < 4; ++pi) {
        float rrow[4] = {Rr.x, Rr.y, Rr.z, Rr.w};
        #pragma unroll
        for (int q = 0; q < 4; ++q) {
            float acc = (pi == p) ? rrow[q] : 0.f;   // own R row, added once
            #pragma unroll
            for (int il = 0; il < 2; ++il)
                acc += hs[pi*2+il] * A[il*4+q];
            s[pi*4+q] = acc;
        }
    }
    #pragma unroll
    for (int x = 0; x < 16; ++x) s[x] += __shfl_xor(s[x], 1, 64);
    #pragma unroll
    for (int x = 0; x < 16; ++x) s[x] += __shfl_xor(s[x], 2, 64);

    // ---- invert S (4x4 SPD), unrolled Gauss-Jordan ----
    float is[16] = {1.f,0.f,0.f,0.f, 0.f,1.f,0.f,0.f, 0.f,0.f,1.f,0.f, 0.f,0.f,0.f,1.f};
    #pragma unroll
    for (int c = 0; c < 4; ++c) {
        float pinv = 1.0f / s[c*4+c];
        #pragma unroll
        for (int k = 0; k < 4; ++k) { s[c*4+k] *= pinv; is[c*4+k] *= pinv; }
        #pragma unroll
        for (int r = 0; r < 4; ++r) {
            if (r != c) {
                float fac = s[r*4+c];
                #pragma unroll
                for (int k = 0; k < 4; ++k) {
                    s[r*4+k]  -= fac * s[c*4+k];
                    is[r*4+k] -= fac * is[c*4+k];
                }
            }
        }
    }

    // ---- KG own 2 rows = A @ inv(S); store (wave-contiguous) ----
    float4* outg = reinterpret_cast<float4*>(out)
                 + (size_t)(b0 + b_loc) * 8 + 2 * p;
    #pragma unroll
    for (int il = 0; il < 2; ++il) {
        float4 o;
        o.x = A[il*4+0]*is[0] + A[il*4+1]*is[4] + A[il*4+2]*is[8]  + A[il*4+3]*is[12];
        o.y = A[il*4+0]*is[1] + A[il*4+1]*is[5] + A[il*4+2]*is[9]  + A[il*4+3]*is[13];
        o.z = A[il*4+0]*is[2] + A[il*4+1]*is[6] + A[il*4+2]*is[10] + A[il*4+3]*is[14];
        o.w = A[il*4+0]*is[3] + A[il*4+1]*is[7] + A[il*4+2]*is[11] + A[il*4+3]*is[15];
        outg[il] = o;
    }
}

extern "C" void kernel_launch(void* const* d_in, const int* in_sizes, int n_in,
                              void* d_out, int out_size, void* d_ws, size_t ws_size,
                              hipStream_t stream) {
    const float* F  = (const float*)d_in[0];
    const float* H  = (const float*)d_in[1];
    const float* Sp = (const float*)d_in[2];
    const float* Q  = (const float*)d_in[3];
    const float* R  = (const float*)d_in[4];
    float* out = (float*)d_out;

    int nb = in_sizes[0] / 64;          // B = 262144 (divisible by 16)
    int blocks = nb / NBB;              // 16384
    kalman_gain_kernel<<<blocks, THREADS, 0, stream>>>(F, H, Sp, Q, R, out, nb);
}